// Round 23
// baseline (64.846 us; speedup 1.0000x reference)
//
#include <hip/hip_runtime.h>

#define IN_FEATS 256
#define HID 32
#define NUM_EMBED 54012
#define N_NODES 65536
#define N_EDGES 1048576
#define BATCH 4096

#define NR 256               // node ranges (dst >> 8), 256 nodes each
#define NB 512               // binsort blocks
#define EPB (N_EDGES / NB)   // 2048 edges per block
#define PBCAP 24             // per-(block,range) slots; ~Pois(8), P(>24)~1e-7
#define HCAP 24              // bin slots per (node, half)
#define OVF_CAP 65536
#define GEMMB 844            // 3376 row-tiles / 4 waves per block
#define NTILE 3376           // ceil(54012/16)
#define W1P 280              // padded k-stride (u16) for W1t LDS

typedef unsigned short u16t;
typedef unsigned int u32t;
typedef __attribute__((ext_vector_type(8))) short bf16x8;
typedef __attribute__((ext_vector_type(4))) float f32x4;

__device__ __forceinline__ float bf2f(u16t u) {
    return __uint_as_float(((u32t)u) << 16);
}
__device__ __forceinline__ u16t f2bf(float f) {
    u32t x = __float_as_uint(f);
    return (u16t)((x + 0x7FFFu + ((x >> 16) & 1u)) >> 16);   // RNE
}
__device__ __forceinline__ u32t cvt_pk(float lo, float hi) {
    u32t r;
    asm("v_cvt_pk_bf16_f32 %0, %1, %2" : "=v"(r) : "v"(lo), "v"(hi));
    return r;
}

// --- 2-col (u32 = bf16x2) half-cell sum: rows of 16 u32, cp = pair idx
__device__ __forceinline__ void hsum_bf2(const int4* cell, int m,
                                         const u32t* __restrict__ rows, int cp,
                                         float& ax, float& ay) {
    int4 c0 = cell[0];
    u32t w[4] = {(u32t)c0.x, (u32t)c0.y, (u32t)c0.z, (u32t)c0.w};
    u32t vv[8];
#pragma unroll
    for (int k = 0; k < 4; ++k) {
        vv[2 * k + 0] = rows[((size_t)(w[k] & 0xFFFFu) << 4) + cp];
        vv[2 * k + 1] = rows[((size_t)(w[k] >> 16) << 4) + cp];
    }
#pragma unroll
    for (int j = 0; j < 8; ++j) {
        ax += (m > j) ? bf2f((u16t)(vv[j] & 0xFFFFu)) : 0.f;
        ay += (m > j) ? bf2f((u16t)(vv[j] >> 16)) : 0.f;
    }
    if (m > 8) {
        int4 c1 = cell[1];
        u32t x[4] = {(u32t)c1.x, (u32t)c1.y, (u32t)c1.z, (u32t)c1.w};
        u32t vb[8];
#pragma unroll
        for (int k = 0; k < 4; ++k) {
            vb[2 * k + 0] = rows[((size_t)(x[k] & 0xFFFFu) << 4) + cp];
            vb[2 * k + 1] = rows[((size_t)(x[k] >> 16) << 4) + cp];
        }
#pragma unroll
        for (int j = 0; j < 8; ++j) {
            ax += (m > 8 + j) ? bf2f((u16t)(vb[j] & 0xFFFFu)) : 0.f;
            ay += (m > 8 + j) ? bf2f((u16t)(vb[j] >> 16)) : 0.f;
        }
        if (m > 16) {
            int4 c2 = cell[2];
            u32t y[4] = {(u32t)c2.x, (u32t)c2.y, (u32t)c2.z, (u32t)c2.w};
            u32t vc[8];
#pragma unroll
            for (int k = 0; k < 4; ++k) {
                vc[2 * k + 0] = rows[((size_t)(y[k] & 0xFFFFu) << 4) + cp];
                vc[2 * k + 1] = rows[((size_t)(y[k] >> 16) << 4) + cp];
            }
#pragma unroll
            for (int j = 0; j < 8; ++j) {
                ax += (m > 16 + j) ? bf2f((u16t)(vc[j] & 0xFFFFu)) : 0.f;
                ay += (m > 16 + j) ? bf2f((u16t)(vc[j] >> 16)) : 0.f;
            }
        }
    }
}

// ---------------------------------------------------------------------------
// Phase A (fused, blockIdx-dispatched):
//   [0, NB)            : binsort — int4 edge loads, LDS cells, coalesced flush
//   [NB, NB+GEMMB)     : tmpb[54012][32] = bf16(embed @ W1) via MFMA 16x16x32
//   [NB+GEMMB, +65)    : fold W2/Wfc/b2/bfc -> M1, M2, bias (+ ovf_cnt init)
// ---------------------------------------------------------------------------
__global__ void k_phaseA(const float* __restrict__ embed, const float* __restrict__ W1,
                         u16t* __restrict__ tmpb,
                         const int* __restrict__ src, const int* __restrict__ dst,
                         u32t* __restrict__ subseg, u16t* __restrict__ hcnt,
                         int* __restrict__ ovf_cnt, int* __restrict__ ovf,
                         const float* __restrict__ W2, const float* __restrict__ b2,
                         const float* __restrict__ Wfc, const float* __restrict__ bfc,
                         float* __restrict__ M1, float* __restrict__ M2,
                         float* __restrict__ bias) {
    __shared__ __align__(16) u32t smem4[256 + NR * PBCAP];   // 25600 B
    int b = blockIdx.x;
    int t = threadIdx.x;

    if (b < NB) {
        // ---------------- binsort (int4 loads, coalesced flush) ----------------
        int bb = b;
        u32t* cur   = smem4;          // [256]
        u32t* cells = smem4 + 256;    // [256][PBCAP]
        cur[t] = 0;
        __syncthreads();
        int base = bb * EPB;
        const int4* s4p = (const int4*)(src + base);
        const int4* d4p = (const int4*)(dst + base);
#pragma unroll
        for (int k = 0; k < EPB / 1024; ++k) {   // 2 iters x 4 edges
            int i = k * 256 + t;
            int4 s4 = s4p[i];
            int4 d4 = d4p[i];
#define DOE(SS, DD) { \
            int r = (DD) >> 8; \
            u32t w = (u32t)(SS) | ((u32t)((DD) & 255) << 16); \
            u32t p = atomicAdd(&cur[r], 1u); \
            if (p < PBCAP) { \
                cells[r * PBCAP + p] = w; \
            } else { \
                int o = atomicAdd(ovf_cnt, 1); \
                if (o < OVF_CAP) ovf[o] = (int)((u32t)(SS) | ((u32t)(DD) << 16)); \
            } }
            DOE(s4.x, d4.x)
            DOE(s4.y, d4.y)
            DOE(s4.z, d4.z)
            DOE(s4.w, d4.w)
#undef DOE
        }
        __syncthreads();
        hcnt[t * NB + bb] = (u16t)min(cur[t], (u32t)PBCAP);
        u32t* dstp = subseg + (size_t)bb * (NR * PBCAP);
        for (int i = t; i < NR * PBCAP; i += 256)
            __builtin_nontemporal_store(cells[i], &dstp[i]);
    } else if (b < NB + GEMMB) {
        // ---------------- MFMA GEMM: tmpb = bf16(embed @ W1) ----------------
        u16t* w1t = (u16t*)smem4;   // [32 cols][W1P k]
        for (int i = t; i < IN_FEATS * HID; i += 256) {
            int k = i >> 5, c = i & 31;
            w1t[c * W1P + k] = f2bf(W1[i]);
        }
        __syncthreads();

        int lane = t & 63;
        int wv = t >> 6;
        int tile = (b - NB) * 4 + wv;
        if (tile >= NTILE) return;
        int r0 = tile * 16;

        int arow = min(r0 + (lane & 15), NUM_EMBED - 1);
        int kq = (lane >> 4) * 8;
        const float* Erow = embed + (size_t)arow * IN_FEATS + kq;

        int c = lane & 15;
        bf16x8 bf0[8], bf1[8];
        {
            const u16t* bp0 = w1t + (size_t)c * W1P + kq;
            const u16t* bp1 = w1t + (size_t)(c + 16) * W1P + kq;
#pragma unroll
            for (int kk = 0; kk < 8; ++kk) {
                bf0[kk] = *(const bf16x8*)(bp0 + kk * 32);
                bf1[kk] = *(const bf16x8*)(bp1 + kk * 32);
            }
        }

        f32x4 acc0 = {0.f, 0.f, 0.f, 0.f};
        f32x4 acc1 = {0.f, 0.f, 0.f, 0.f};
#pragma unroll
        for (int kk = 0; kk < 8; ++kk) {
            float4 p = *(const float4*)(Erow + kk * 32);
            float4 q = *(const float4*)(Erow + kk * 32 + 4);
            union { bf16x8 v; u32t u[4]; } a;
            a.u[0] = cvt_pk(p.x, p.y);
            a.u[1] = cvt_pk(p.z, p.w);
            a.u[2] = cvt_pk(q.x, q.y);
            a.u[3] = cvt_pk(q.z, q.w);
            acc0 = __builtin_amdgcn_mfma_f32_16x16x32_bf16(a.v, bf0[kk], acc0, 0, 0, 0);
            acc1 = __builtin_amdgcn_mfma_f32_16x16x32_bf16(a.v, bf1[kk], acc1, 0, 0, 0);
        }

        int rbase = r0 + (lane >> 4) * 4;
#pragma unroll
        for (int j = 0; j < 4; ++j) {
            int rr = rbase + j;
            if (rr < NUM_EMBED) {
                tmpb[(size_t)rr * HID + c]      = f2bf(acc0[j]);
                tmpb[(size_t)rr * HID + 16 + c] = f2bf(acc1[j]);
            }
        }
    } else {
        // ---------------- fold (4 independent accumulators) ----------------
        int r = b - NB - GEMMB;   // 0..64
        int c = t;
        if (r < 32) {
            float p0 = 0.f, p1 = 0.f, p2 = 0.f, p3 = 0.f;
#pragma unroll
            for (int j = 0; j < 256; j += 4) {
                p0 += W2[r * 256 + j + 0] * Wfc[(j + 0) * 256 + c];
                p1 += W2[r * 256 + j + 1] * Wfc[(j + 1) * 256 + c];
                p2 += W2[r * 256 + j + 2] * Wfc[(j + 2) * 256 + c];
                p3 += W2[r * 256 + j + 3] * Wfc[(j + 3) * 256 + c];
            }
            M1[r * 256 + c] = (p0 + p1) + (p2 + p3);
        } else if (r < 64) {
            int k = r - 32;
            float p0 = 0.f, p1 = 0.f, p2 = 0.f, p3 = 0.f;
#pragma unroll
            for (int j = 0; j < 256; j += 4) {
                p0 += W2[k * 256 + j + 0] * Wfc[(256 + j + 0) * 256 + c];
                p1 += W2[k * 256 + j + 1] * Wfc[(256 + j + 1) * 256 + c];
                p2 += W2[k * 256 + j + 2] * Wfc[(256 + j + 2) * 256 + c];
                p3 += W2[k * 256 + j + 3] * Wfc[(256 + j + 3) * 256 + c];
            }
            M2[k * 256 + c] = (p0 + p1) + (p2 + p3);
        } else {
            if (t == 0) *ovf_cnt = 0;   // fused init (binsort overflow P ~1e-7)
            float p0 = 0.f, p1 = 0.f;
#pragma unroll
            for (int j = 0; j < 256; j += 2) {
                p0 += b2[j + 0] * (Wfc[(j + 0) * 256 + c] + Wfc[(256 + j + 0) * 256 + c]);
                p1 += b2[j + 1] * (Wfc[(j + 1) * 256 + c] + Wfc[(256 + j + 1) * 256 + c]);
            }
            bias[c] = bfc[c] + p0 + p1;
        }
    }
}

// ---------------------------------------------------------------------------
// Phase B (fused):
//   [0, 2*NR)      : pack half — block-major subseg, 8-deep batched loads ->
//                    LDS cells [256 nodes][24 u16], flush to bins2 + cntAB.
//   [2*NR, +4096)  : gather — feat1[n][:] = tmpb[idx[n]][:]
// ---------------------------------------------------------------------------
__global__ void k_phaseB(const u32t* __restrict__ subseg, const u16t* __restrict__ hcnt,
                         u32t* __restrict__ cntAB, u16t* __restrict__ bins2,
                         int* __restrict__ ovf_cnt, int* __restrict__ ovf,
                         const u32t* __restrict__ tmpu, const int* __restrict__ idx,
                         u32t* __restrict__ feat1u) {
    __shared__ u16t cells[NR * HCAP];   // 12 KB
    __shared__ u32t cl[NR];             // 1 KB
    __shared__ u16t hc[NB / 2];         // 512 B
    int b = blockIdx.x;
    int t = threadIdx.x;
    if (b < 2 * NR) {
        int r = b >> 1, h = b & 1;
        for (int i = t; i < NR * HCAP / 2; i += 256) ((u32t*)cells)[i] = 0;
        cl[t] = 0;
        if (t < 128)
            ((u32t*)hc)[t] = ((const u32t*)(hcnt + (size_t)r * NB + h * 256))[t];
        __syncthreads();

        const u32t* segbase = subseg + ((size_t)(h * 256) * NR + r) * PBCAP;
        for (int base_lin = 0; base_lin < 256 * PBCAP; base_lin += 2048) {
            u32t wbuf[8];
            int vld[8];
#pragma unroll
            for (int u = 0; u < 8; ++u) {
                int lin = base_lin + u * 256 + t;
                int bb = lin / PBCAP;
                int slot = lin - bb * PBCAP;
                vld[u] = (slot < (int)hc[bb]);
                wbuf[u] = __builtin_nontemporal_load(
                    &segbase[(size_t)bb * (NR * PBCAP) + slot]);
            }
#pragma unroll
            for (int u = 0; u < 8; ++u) {
                if (vld[u]) {
                    u32t w = wbuf[u];
                    int dl = (int)(w >> 16) & 255;
                    u32t p = atomicAdd(&cl[dl], 1u);
                    if (p < HCAP) {
                        cells[dl * HCAP + p] = (u16t)(w & 0xFFFFu);
                    } else {
                        int o = atomicAdd(ovf_cnt, 1);
                        u32t dfull = ((u32t)r << 8) | (u32t)dl;
                        if (o < OVF_CAP) ovf[o] = (int)((w & 0xFFFFu) | (dfull << 16));
                    }
                }
            }
        }
        __syncthreads();
        u32t* dst32 = (u32t*)(bins2) + ((size_t)h * N_NODES + ((size_t)r << 8)) * (HCAP / 2);
        for (int i = t; i < NR * HCAP / 2; i += 256)
            dst32[i] = ((const u32t*)cells)[i];
        ((u16t*)cntAB)[(((size_t)r << 8) + t) * 2 + h] = (u16t)min(cl[t], 65535u);
    } else {
        int i = (b - 2 * NR) * 256 + t;
        int n = i >> 4, j = i & 15;
        feat1u[((size_t)n << 4) + j] = tmpu[((size_t)idx[n] << 4) + j];
    }
}

// ---------------------------------------------------------------------------
// SpMM1 (16 lanes/node, u32 = 2 bf16 cols per lane):
//   agg1b[v][cp] = cvt_pk(relu(sum + b1)) — bf16-packed output
// ---------------------------------------------------------------------------
__global__ void k_spmm1(const u32t* __restrict__ feat1u,
                        const u32t* __restrict__ cntAB, const u16t* __restrict__ bins2,
                        const int* __restrict__ ovf_cnt, const int* __restrict__ ovf,
                        const float* __restrict__ b1, u32t* __restrict__ agg1b) {
    int t = blockIdx.x * 256 + threadIdx.x;
    int v = t >> 4, cp = t & 15;
    u32t cw = cntAB[v];
    int mA = min((int)(cw & 0xFFFFu), HCAP);
    int mB = min((int)(cw >> 16), HCAP);
    const int4* cellA = (const int4*)((const u16t*)bins2 + (size_t)v * HCAP);
    const int4* cellB = (const int4*)((const u16t*)bins2 + ((size_t)N_NODES + v) * HCAP);
    float ax = 0.f, ay = 0.f;
    hsum_bf2(cellA, mA, feat1u, cp, ax, ay);
    hsum_bf2(cellB, mB, feat1u, cp, ax, ay);

    int total = min(*ovf_cnt, OVF_CAP);
    for (int i = 0; i < total; ++i) {
        u32t e = (u32t)ovf[i];
        if ((e >> 16) == (u32t)v) {
            u32t w = feat1u[((size_t)(e & 0xFFFFu) << 4) + cp];
            ax += bf2f((u16t)(w & 0xFFFFu));
            ay += bf2f((u16t)(w >> 16));
        }
    }
    float2 bb = ((const float2*)b1)[cp];
    agg1b[((size_t)v << 4) + cp] = cvt_pk(fmaxf(ax + bb.x, 0.f), fmaxf(ay + bb.y, 0.f));
}

// ---------------------------------------------------------------------------
// K_tail: fused spmm2 (2 sides x 8 slots x 16 lanes) + final GEMM.
// agg1 rows are bf16-packed (64B) — same hsum_bf2 path.
// ---------------------------------------------------------------------------
__global__ void k_tail(const u32t* __restrict__ agg1b,
                       const u32t* __restrict__ cntAB, const u16t* __restrict__ bins2,
                       const int* __restrict__ ovf_cnt, const int* __restrict__ ovf,
                       const int* __restrict__ g1, const int* __restrict__ g2,
                       const float* __restrict__ M1, const float* __restrict__ M2,
                       const float* __restrict__ bias,
                       float* __restrict__ out) {
    __shared__ float a1s[8][HID];
    __shared__ float a2s[8][HID];
    int i0 = blockIdx.x * 8;
    int tid = threadIdx.x;
    int grp = tid >> 4;          // 0..15: side*8 + sg
    int cp  = tid & 15;
    int side = grp >> 3;
    int sg   = grp & 7;
    int slot = i0 + sg;
    int v = side ? g2[slot] : g1[slot];
    u32t cw = cntAB[v];
    int mA = min((int)(cw & 0xFFFFu), HCAP);
    int mB = min((int)(cw >> 16), HCAP);
    const int4* cellA = (const int4*)((const u16t*)bins2 + (size_t)v * HCAP);
    const int4* cellB = (const int4*)((const u16t*)bins2 + ((size_t)N_NODES + v) * HCAP);
    float ax = 0.f, ay = 0.f;
    hsum_bf2(cellA, mA, agg1b, cp, ax, ay);
    hsum_bf2(cellB, mB, agg1b, cp, ax, ay);

    int total = min(*ovf_cnt, OVF_CAP);
    for (int i = 0; i < total; ++i) {
        u32t e = (u32t)ovf[i];
        if ((e >> 16) == (u32t)v) {
            u32t w = agg1b[((size_t)(e & 0xFFFFu) << 4) + cp];
            ax += bf2f((u16t)(w & 0xFFFFu));
            ay += bf2f((u16t)(w >> 16));
        }
    }
    float* dstb = side ? a2s[sg] : a1s[sg];
    dstb[2 * cp + 0] = ax;
    dstb[2 * cp + 1] = ay;
    __syncthreads();

    int cc = tid;
    float acc[8];
#pragma unroll
    for (int q = 0; q < 8; ++q) acc[q] = bias[cc];
#pragma unroll
    for (int k = 0; k < HID; ++k) {
        float m1 = M1[k * 256 + cc];
        float m2 = M2[k * 256 + cc];
#pragma unroll
        for (int q = 0; q < 8; ++q)
            acc[q] += a1s[q][k] * m1 + a2s[q][k] * m2;
    }
#pragma unroll
    for (int q = 0; q < 8; ++q)
        out[(size_t)(i0 + q) * 256 + cc] = fmaxf(acc[q], 0.f);
}

// ---------------------------------------------------------------------------
extern "C" void kernel_launch(void* const* d_in, const int* in_sizes, int n_in,
                              void* d_out, int out_size, void* d_ws, size_t ws_size,
                              hipStream_t stream) {
    const int*   idx   = (const int*)d_in[0];
    const int*   src   = (const int*)d_in[1];
    const int*   dst   = (const int*)d_in[2];
    const int*   g1    = (const int*)d_in[3];
    const int*   g2    = (const int*)d_in[4];
    const float* embed = (const float*)d_in[5];
    const float* W1    = (const float*)d_in[6];
    const float* b1    = (const float*)d_in[7];
    const float* W2    = (const float*)d_in[8];
    const float* b2    = (const float*)d_in[9];
    const float* Wfc   = (const float*)d_in[10];
    const float* bfc   = (const float*)d_in[11];
    float* out = (float*)d_out;

    char* ws = (char*)d_ws;
    u16t*  tmpb     = (u16t*)ws;   ws += (size_t)NUM_EMBED * HID * 2 + 64;   // 3.5 MB
    u16t*  feat1    = (u16t*)ws;   ws += (size_t)N_NODES * HID * 2;          // 4 MB
    u32t*  agg1b    = (u32t*)ws;   ws += (size_t)N_NODES * HID * 2;          // 4 MB (bf16 pairs)
    float* M1       = (float*)ws;  ws += 32 * 256 * 4;
    float* M2       = (float*)ws;  ws += 32 * 256 * 4;
    float* bias     = (float*)ws;  ws += 256 * 4;
    u32t*  subseg   = (u32t*)ws;   ws += (size_t)NB * NR * PBCAP * 4;        // 12.6 MB
    u16t*  hcnt     = (u16t*)ws;   ws += (size_t)NR * NB * 2;                // 256 KB
    u32t*  cntAB    = (u32t*)ws;   ws += (size_t)N_NODES * 4;                // 256 KB
    u16t*  bins2    = (u16t*)ws;   ws += (size_t)2 * N_NODES * HCAP * 2;     // 6 MB
    int*   ovf_cnt  = (int*)ws;    ws += 64;
    int*   ovf      = (int*)ws;    ws += (size_t)OVF_CAP * 4;                // 256 KB

    k_phaseA<<<NB + GEMMB + 65, 256, 0, stream>>>(embed, W1, tmpb,
                                                  src, dst, subseg, hcnt, ovf_cnt, ovf,
                                                  W2, b2, Wfc, bfc, M1, M2, bias);

    k_phaseB<<<2 * NR + (N_NODES * 16) / 256, 256, 0, stream>>>(subseg, hcnt,
                                                                cntAB, bins2,
                                                                ovf_cnt, ovf,
                                                                (const u32t*)tmpb, idx,
                                                                (u32t*)feat1);

    k_spmm1<<<(N_NODES * 16) / 256, 256, 0, stream>>>((const u32t*)feat1, cntAB, bins2,
                                                      ovf_cnt, ovf, b1, agg1b);

    k_tail<<<BATCH / 8, 256, 0, stream>>>(agg1b, cntAB, bins2,
                                          ovf_cnt, ovf, g1, g2, M1, M2, bias, out);
}

// Round 24
// 63.293 us; speedup vs baseline: 1.0245x; 1.0245x over previous
//
#include <hip/hip_runtime.h>

#define IN_FEATS 256
#define HID 32
#define NUM_EMBED 54012
#define N_NODES 65536
#define N_EDGES 1048576
#define BATCH 4096

#define NR 256               // node ranges (dst >> 8), 256 nodes each
#define NB 512               // binsort blocks
#define EPB (N_EDGES / NB)   // 2048 edges per block
#define PBCAP 24             // per-(block,range) slots; ~Pois(8), P(>24)~1e-7
#define HCAP 24              // bin slots per (node, half)
#define OVF_CAP 65536
#define GEMMB 844            // 3376 row-tiles / 4 waves per block
#define NTILE 3376           // ceil(54012/16)
#define W1P 280              // padded k-stride (u16) for W1t LDS

typedef unsigned short u16t;
typedef unsigned int u32t;
typedef __attribute__((ext_vector_type(8))) short bf16x8;
typedef __attribute__((ext_vector_type(4))) float f32x4;

__device__ __forceinline__ float bf2f(u16t u) {
    return __uint_as_float(((u32t)u) << 16);
}
__device__ __forceinline__ u16t f2bf(float f) {
    u32t x = __float_as_uint(f);
    return (u16t)((x + 0x7FFFu + ((x >> 16) & 1u)) >> 16);   // RNE
}
__device__ __forceinline__ u32t cvt_pk(float lo, float hi) {
    u32t r;
    asm("v_cvt_pk_bf16_f32 %0, %1, %2" : "=v"(r) : "v"(lo), "v"(hi));
    return r;
}

// --- 2-col (u32 = bf16x2) half-cell sum: rows of 16 u32, cp = pair idx
__device__ __forceinline__ void hsum_bf2(const int4* cell, int m,
                                         const u32t* __restrict__ rows, int cp,
                                         float& ax, float& ay) {
    int4 c0 = cell[0];
    u32t w[4] = {(u32t)c0.x, (u32t)c0.y, (u32t)c0.z, (u32t)c0.w};
    u32t vv[8];
#pragma unroll
    for (int k = 0; k < 4; ++k) {
        vv[2 * k + 0] = rows[((size_t)(w[k] & 0xFFFFu) << 4) + cp];
        vv[2 * k + 1] = rows[((size_t)(w[k] >> 16) << 4) + cp];
    }
#pragma unroll
    for (int j = 0; j < 8; ++j) {
        ax += (m > j) ? bf2f((u16t)(vv[j] & 0xFFFFu)) : 0.f;
        ay += (m > j) ? bf2f((u16t)(vv[j] >> 16)) : 0.f;
    }
    if (m > 8) {
        int4 c1 = cell[1];
        u32t x[4] = {(u32t)c1.x, (u32t)c1.y, (u32t)c1.z, (u32t)c1.w};
        u32t vb[8];
#pragma unroll
        for (int k = 0; k < 4; ++k) {
            vb[2 * k + 0] = rows[((size_t)(x[k] & 0xFFFFu) << 4) + cp];
            vb[2 * k + 1] = rows[((size_t)(x[k] >> 16) << 4) + cp];
        }
#pragma unroll
        for (int j = 0; j < 8; ++j) {
            ax += (m > 8 + j) ? bf2f((u16t)(vb[j] & 0xFFFFu)) : 0.f;
            ay += (m > 8 + j) ? bf2f((u16t)(vb[j] >> 16)) : 0.f;
        }
        if (m > 16) {
            int4 c2 = cell[2];
            u32t y[4] = {(u32t)c2.x, (u32t)c2.y, (u32t)c2.z, (u32t)c2.w};
            u32t vc[8];
#pragma unroll
            for (int k = 0; k < 4; ++k) {
                vc[2 * k + 0] = rows[((size_t)(y[k] & 0xFFFFu) << 4) + cp];
                vc[2 * k + 1] = rows[((size_t)(y[k] >> 16) << 4) + cp];
            }
#pragma unroll
            for (int j = 0; j < 8; ++j) {
                ax += (m > 16 + j) ? bf2f((u16t)(vc[j] & 0xFFFFu)) : 0.f;
                ay += (m > 16 + j) ? bf2f((u16t)(vc[j] >> 16)) : 0.f;
            }
        }
    }
}

// ---------------------------------------------------------------------------
// Phase A (fused, blockIdx-dispatched):
//   [0, NB)            : binsort — scalar nt edge loads, LDS cells, coalesced
//                        flush to block-major subseg. Zero global atomics.
//   [NB, NB+GEMMB)     : tmpb[54012][32] = bf16(embed @ W1) via MFMA 16x16x32
//   [NB+GEMMB, +65)    : fold W2/Wfc/b2/bfc -> M1, M2, bias (+ ovf_cnt init)
// ---------------------------------------------------------------------------
__global__ void k_phaseA(const float* __restrict__ embed, const float* __restrict__ W1,
                         u16t* __restrict__ tmpb,
                         const int* __restrict__ src, const int* __restrict__ dst,
                         u32t* __restrict__ subseg, u16t* __restrict__ hcnt,
                         int* __restrict__ ovf_cnt, int* __restrict__ ovf,
                         const float* __restrict__ W2, const float* __restrict__ b2,
                         const float* __restrict__ Wfc, const float* __restrict__ bfc,
                         float* __restrict__ M1, float* __restrict__ M2,
                         float* __restrict__ bias) {
    __shared__ __align__(16) u32t smem4[256 + NR * PBCAP];   // 25600 B
    int b = blockIdx.x;
    int t = threadIdx.x;

    if (b < NB) {
        // ---------------- binsort (single pass, coalesced flush) ----------------
        int bb = b;
        u32t* cur   = smem4;          // [256]
        u32t* cells = smem4 + 256;    // [256][PBCAP]
        cur[t] = 0;
        __syncthreads();
        int base = bb * EPB;
#pragma unroll
        for (int k = 0; k < EPB / 256; ++k) {
            int i = k * 256 + t;
            int s = __builtin_nontemporal_load(&src[base + i]);
            int d = __builtin_nontemporal_load(&dst[base + i]);
            int r = d >> 8;
            u32t w = (u32t)s | ((u32t)(d & 255) << 16);
            u32t p = atomicAdd(&cur[r], 1u);
            if (p < PBCAP) {
                cells[r * PBCAP + p] = w;
            } else {
                int o = atomicAdd(ovf_cnt, 1);
                if (o < OVF_CAP) ovf[o] = (int)((u32t)s | ((u32t)d << 16));
            }
        }
        __syncthreads();
        hcnt[t * NB + bb] = (u16t)min(cur[t], (u32t)PBCAP);
        u32t* dstp = subseg + (size_t)bb * (NR * PBCAP);
        for (int i = t; i < NR * PBCAP; i += 256)
            __builtin_nontemporal_store(cells[i], &dstp[i]);
    } else if (b < NB + GEMMB) {
        // ---------------- MFMA GEMM: tmpb = bf16(embed @ W1) ----------------
        u16t* w1t = (u16t*)smem4;   // [32 cols][W1P k]
        for (int i = t; i < IN_FEATS * HID; i += 256) {
            int k = i >> 5, c = i & 31;
            w1t[c * W1P + k] = f2bf(W1[i]);
        }
        __syncthreads();

        int lane = t & 63;
        int wv = t >> 6;
        int tile = (b - NB) * 4 + wv;
        if (tile >= NTILE) return;
        int r0 = tile * 16;

        int arow = min(r0 + (lane & 15), NUM_EMBED - 1);
        int kq = (lane >> 4) * 8;
        const float* Erow = embed + (size_t)arow * IN_FEATS + kq;

        int c = lane & 15;
        bf16x8 bf0[8], bf1[8];
        {
            const u16t* bp0 = w1t + (size_t)c * W1P + kq;
            const u16t* bp1 = w1t + (size_t)(c + 16) * W1P + kq;
#pragma unroll
            for (int kk = 0; kk < 8; ++kk) {
                bf0[kk] = *(const bf16x8*)(bp0 + kk * 32);
                bf1[kk] = *(const bf16x8*)(bp1 + kk * 32);
            }
        }

        f32x4 acc0 = {0.f, 0.f, 0.f, 0.f};
        f32x4 acc1 = {0.f, 0.f, 0.f, 0.f};
#pragma unroll
        for (int kk = 0; kk < 8; ++kk) {
            float4 p = *(const float4*)(Erow + kk * 32);
            float4 q = *(const float4*)(Erow + kk * 32 + 4);
            union { bf16x8 v; u32t u[4]; } a;
            a.u[0] = cvt_pk(p.x, p.y);
            a.u[1] = cvt_pk(p.z, p.w);
            a.u[2] = cvt_pk(q.x, q.y);
            a.u[3] = cvt_pk(q.z, q.w);
            acc0 = __builtin_amdgcn_mfma_f32_16x16x32_bf16(a.v, bf0[kk], acc0, 0, 0, 0);
            acc1 = __builtin_amdgcn_mfma_f32_16x16x32_bf16(a.v, bf1[kk], acc1, 0, 0, 0);
        }

        int rbase = r0 + (lane >> 4) * 4;
#pragma unroll
        for (int j = 0; j < 4; ++j) {
            int rr = rbase + j;
            if (rr < NUM_EMBED) {
                tmpb[(size_t)rr * HID + c]      = f2bf(acc0[j]);
                tmpb[(size_t)rr * HID + 16 + c] = f2bf(acc1[j]);
            }
        }
    } else {
        // ---------------- fold (4 independent accumulators) ----------------
        int r = b - NB - GEMMB;   // 0..64
        int c = t;
        if (r < 32) {
            float p0 = 0.f, p1 = 0.f, p2 = 0.f, p3 = 0.f;
#pragma unroll
            for (int j = 0; j < 256; j += 4) {
                p0 += W2[r * 256 + j + 0] * Wfc[(j + 0) * 256 + c];
                p1 += W2[r * 256 + j + 1] * Wfc[(j + 1) * 256 + c];
                p2 += W2[r * 256 + j + 2] * Wfc[(j + 2) * 256 + c];
                p3 += W2[r * 256 + j + 3] * Wfc[(j + 3) * 256 + c];
            }
            M1[r * 256 + c] = (p0 + p1) + (p2 + p3);
        } else if (r < 64) {
            int k = r - 32;
            float p0 = 0.f, p1 = 0.f, p2 = 0.f, p3 = 0.f;
#pragma unroll
            for (int j = 0; j < 256; j += 4) {
                p0 += W2[k * 256 + j + 0] * Wfc[(256 + j + 0) * 256 + c];
                p1 += W2[k * 256 + j + 1] * Wfc[(256 + j + 1) * 256 + c];
                p2 += W2[k * 256 + j + 2] * Wfc[(256 + j + 2) * 256 + c];
                p3 += W2[k * 256 + j + 3] * Wfc[(256 + j + 3) * 256 + c];
            }
            M2[k * 256 + c] = (p0 + p1) + (p2 + p3);
        } else {
            if (t == 0) *ovf_cnt = 0;   // fused init (binsort overflow P ~1e-7)
            float p0 = 0.f, p1 = 0.f;
#pragma unroll
            for (int j = 0; j < 256; j += 2) {
                p0 += b2[j + 0] * (Wfc[(j + 0) * 256 + c] + Wfc[(256 + j + 0) * 256 + c]);
                p1 += b2[j + 1] * (Wfc[(j + 1) * 256 + c] + Wfc[(256 + j + 1) * 256 + c]);
            }
            bias[c] = bfc[c] + p0 + p1;
        }
    }
}

// ---------------------------------------------------------------------------
// Phase B (fused):
//   [0, 2*NR)      : pack half — block-major subseg, 8-deep batched loads ->
//                    LDS cells [256 nodes][24 u16], flush to bins2 + cntAB.
//   [2*NR, +4096)  : gather — feat1[n][:] = tmpb[idx[n]][:]
// ---------------------------------------------------------------------------
__global__ void k_phaseB(const u32t* __restrict__ subseg, const u16t* __restrict__ hcnt,
                         u32t* __restrict__ cntAB, u16t* __restrict__ bins2,
                         int* __restrict__ ovf_cnt, int* __restrict__ ovf,
                         const u32t* __restrict__ tmpu, const int* __restrict__ idx,
                         u32t* __restrict__ feat1u) {
    __shared__ u16t cells[NR * HCAP];   // 12 KB
    __shared__ u32t cl[NR];             // 1 KB
    __shared__ u16t hc[NB / 2];         // 512 B
    int b = blockIdx.x;
    int t = threadIdx.x;
    if (b < 2 * NR) {
        int r = b >> 1, h = b & 1;
        for (int i = t; i < NR * HCAP / 2; i += 256) ((u32t*)cells)[i] = 0;
        cl[t] = 0;
        if (t < 128)
            ((u32t*)hc)[t] = ((const u32t*)(hcnt + (size_t)r * NB + h * 256))[t];
        __syncthreads();

        const u32t* segbase = subseg + ((size_t)(h * 256) * NR + r) * PBCAP;
        for (int base_lin = 0; base_lin < 256 * PBCAP; base_lin += 2048) {
            u32t wbuf[8];
            int vld[8];
#pragma unroll
            for (int u = 0; u < 8; ++u) {
                int lin = base_lin + u * 256 + t;
                int bb = lin / PBCAP;
                int slot = lin - bb * PBCAP;
                vld[u] = (slot < (int)hc[bb]);
                wbuf[u] = __builtin_nontemporal_load(
                    &segbase[(size_t)bb * (NR * PBCAP) + slot]);
            }
#pragma unroll
            for (int u = 0; u < 8; ++u) {
                if (vld[u]) {
                    u32t w = wbuf[u];
                    int dl = (int)(w >> 16) & 255;
                    u32t p = atomicAdd(&cl[dl], 1u);
                    if (p < HCAP) {
                        cells[dl * HCAP + p] = (u16t)(w & 0xFFFFu);
                    } else {
                        int o = atomicAdd(ovf_cnt, 1);
                        u32t dfull = ((u32t)r << 8) | (u32t)dl;
                        if (o < OVF_CAP) ovf[o] = (int)((w & 0xFFFFu) | (dfull << 16));
                    }
                }
            }
        }
        __syncthreads();
        u32t* dst32 = (u32t*)(bins2) + ((size_t)h * N_NODES + ((size_t)r << 8)) * (HCAP / 2);
        for (int i = t; i < NR * HCAP / 2; i += 256)
            dst32[i] = ((const u32t*)cells)[i];
        ((u16t*)cntAB)[(((size_t)r << 8) + t) * 2 + h] = (u16t)min(cl[t], 65535u);
    } else {
        int i = (b - 2 * NR) * 256 + t;
        int n = i >> 4, j = i & 15;
        feat1u[((size_t)n << 4) + j] = tmpu[((size_t)idx[n] << 4) + j];
    }
}

// ---------------------------------------------------------------------------
// SpMM1 (16 lanes/node, u32 = 2 bf16 cols per lane):
//   agg1b[v][cp] = cvt_pk(relu(sum + b1)) — bf16-packed output
// ---------------------------------------------------------------------------
__global__ void k_spmm1(const u32t* __restrict__ feat1u,
                        const u32t* __restrict__ cntAB, const u16t* __restrict__ bins2,
                        const int* __restrict__ ovf_cnt, const int* __restrict__ ovf,
                        const float* __restrict__ b1, u32t* __restrict__ agg1b) {
    int t = blockIdx.x * 256 + threadIdx.x;
    int v = t >> 4, cp = t & 15;
    u32t cw = cntAB[v];
    int mA = min((int)(cw & 0xFFFFu), HCAP);
    int mB = min((int)(cw >> 16), HCAP);
    const int4* cellA = (const int4*)((const u16t*)bins2 + (size_t)v * HCAP);
    const int4* cellB = (const int4*)((const u16t*)bins2 + ((size_t)N_NODES + v) * HCAP);
    float ax = 0.f, ay = 0.f;
    hsum_bf2(cellA, mA, feat1u, cp, ax, ay);
    hsum_bf2(cellB, mB, feat1u, cp, ax, ay);

    int total = min(*ovf_cnt, OVF_CAP);
    for (int i = 0; i < total; ++i) {
        u32t e = (u32t)ovf[i];
        if ((e >> 16) == (u32t)v) {
            u32t w = feat1u[((size_t)(e & 0xFFFFu) << 4) + cp];
            ax += bf2f((u16t)(w & 0xFFFFu));
            ay += bf2f((u16t)(w >> 16));
        }
    }
    float2 bb = ((const float2*)b1)[cp];
    agg1b[((size_t)v << 4) + cp] = cvt_pk(fmaxf(ax + bb.x, 0.f), fmaxf(ay + bb.y, 0.f));
}

// ---------------------------------------------------------------------------
// K_tail: fused spmm2 (2 sides x 8 slots x 16 lanes) + final GEMM.
// agg1 rows are bf16-packed (64B) — same hsum_bf2 path.
// ---------------------------------------------------------------------------
__global__ void k_tail(const u32t* __restrict__ agg1b,
                       const u32t* __restrict__ cntAB, const u16t* __restrict__ bins2,
                       const int* __restrict__ ovf_cnt, const int* __restrict__ ovf,
                       const int* __restrict__ g1, const int* __restrict__ g2,
                       const float* __restrict__ M1, const float* __restrict__ M2,
                       const float* __restrict__ bias,
                       float* __restrict__ out) {
    __shared__ float a1s[8][HID];
    __shared__ float a2s[8][HID];
    int i0 = blockIdx.x * 8;
    int tid = threadIdx.x;
    int grp = tid >> 4;          // 0..15: side*8 + sg
    int cp  = tid & 15;
    int side = grp >> 3;
    int sg   = grp & 7;
    int slot = i0 + sg;
    int v = side ? g2[slot] : g1[slot];
    u32t cw = cntAB[v];
    int mA = min((int)(cw & 0xFFFFu), HCAP);
    int mB = min((int)(cw >> 16), HCAP);
    const int4* cellA = (const int4*)((const u16t*)bins2 + (size_t)v * HCAP);
    const int4* cellB = (const int4*)((const u16t*)bins2 + ((size_t)N_NODES + v) * HCAP);
    float ax = 0.f, ay = 0.f;
    hsum_bf2(cellA, mA, agg1b, cp, ax, ay);
    hsum_bf2(cellB, mB, agg1b, cp, ax, ay);

    int total = min(*ovf_cnt, OVF_CAP);
    for (int i = 0; i < total; ++i) {
        u32t e = (u32t)ovf[i];
        if ((e >> 16) == (u32t)v) {
            u32t w = agg1b[((size_t)(e & 0xFFFFu) << 4) + cp];
            ax += bf2f((u16t)(w & 0xFFFFu));
            ay += bf2f((u16t)(w >> 16));
        }
    }
    float* dstb = side ? a2s[sg] : a1s[sg];
    dstb[2 * cp + 0] = ax;
    dstb[2 * cp + 1] = ay;
    __syncthreads();

    int cc = tid;
    float acc[8];
#pragma unroll
    for (int q = 0; q < 8; ++q) acc[q] = bias[cc];
#pragma unroll
    for (int k = 0; k < HID; ++k) {
        float m1 = M1[k * 256 + cc];
        float m2 = M2[k * 256 + cc];
#pragma unroll
        for (int q = 0; q < 8; ++q)
            acc[q] += a1s[q][k] * m1 + a2s[q][k] * m2;
    }
#pragma unroll
    for (int q = 0; q < 8; ++q)
        out[(size_t)(i0 + q) * 256 + cc] = fmaxf(acc[q], 0.f);
}

// ---------------------------------------------------------------------------
extern "C" void kernel_launch(void* const* d_in, const int* in_sizes, int n_in,
                              void* d_out, int out_size, void* d_ws, size_t ws_size,
                              hipStream_t stream) {
    const int*   idx   = (const int*)d_in[0];
    const int*   src   = (const int*)d_in[1];
    const int*   dst   = (const int*)d_in[2];
    const int*   g1    = (const int*)d_in[3];
    const int*   g2    = (const int*)d_in[4];
    const float* embed = (const float*)d_in[5];
    const float* W1    = (const float*)d_in[6];
    const float* b1    = (const float*)d_in[7];
    const float* W2    = (const float*)d_in[8];
    const float* b2    = (const float*)d_in[9];
    const float* Wfc   = (const float*)d_in[10];
    const float* bfc   = (const float*)d_in[11];
    float* out = (float*)d_out;

    char* ws = (char*)d_ws;
    u16t*  tmpb     = (u16t*)ws;   ws += (size_t)NUM_EMBED * HID * 2 + 64;   // 3.5 MB
    u16t*  feat1    = (u16t*)ws;   ws += (size_t)N_NODES * HID * 2;          // 4 MB
    u32t*  agg1b    = (u32t*)ws;   ws += (size_t)N_NODES * HID * 2;          // 4 MB (bf16 pairs)
    float* M1       = (float*)ws;  ws += 32 * 256 * 4;
    float* M2       = (float*)ws;  ws += 32 * 256 * 4;
    float* bias     = (float*)ws;  ws += 256 * 4;
    u32t*  subseg   = (u32t*)ws;   ws += (size_t)NB * NR * PBCAP * 4;        // 12.6 MB
    u16t*  hcnt     = (u16t*)ws;   ws += (size_t)NR * NB * 2;                // 256 KB
    u32t*  cntAB    = (u32t*)ws;   ws += (size_t)N_NODES * 4;                // 256 KB
    u16t*  bins2    = (u16t*)ws;   ws += (size_t)2 * N_NODES * HCAP * 2;     // 6 MB
    int*   ovf_cnt  = (int*)ws;    ws += 64;
    int*   ovf      = (int*)ws;    ws += (size_t)OVF_CAP * 4;                // 256 KB

    k_phaseA<<<NB + GEMMB + 65, 256, 0, stream>>>(embed, W1, tmpb,
                                                  src, dst, subseg, hcnt, ovf_cnt, ovf,
                                                  W2, b2, Wfc, bfc, M1, M2, bias);

    k_phaseB<<<2 * NR + (N_NODES * 16) / 256, 256, 0, stream>>>(subseg, hcnt,
                                                                cntAB, bins2,
                                                                ovf_cnt, ovf,
                                                                (const u32t*)tmpb, idx,
                                                                (u32t*)feat1);

    k_spmm1<<<(N_NODES * 16) / 256, 256, 0, stream>>>((const u32t*)feat1, cntAB, bins2,
                                                      ovf_cnt, ovf, b1, agg1b);

    k_tail<<<BATCH / 8, 256, 0, stream>>>(agg1b, cntAB, bins2,
                                          ovf_cnt, ovf, g1, g2, M1, M2, bias, out);
}